// Round 10
// baseline (3023.337 us; speedup 1.0000x reference)
//
#include <hip/hip_runtime.h>
#include <hip/hip_bf16.h>

typedef unsigned short u16;
typedef __bf16 bf16x8 __attribute__((ext_vector_type(8)));
typedef short  short8 __attribute__((ext_vector_type(8)));
typedef float  f32x4  __attribute__((ext_vector_type(4)));
typedef float  f32x16 __attribute__((ext_vector_type(16)));
typedef u16    u16x4  __attribute__((ext_vector_type(4)));

#define BB 2
#define SS 2048
#define DD 2048
#define HH 16
#define HDIM 128
#define MM (BB * SS)   // 4096 tokens
#define KSCALE 0.12752039505554602f

// ---- DIAGNOSTIC amplification (idempotent reps; true time = dur/REP) ----
#define REP_CONV 16
#define REP_QKV  5
#define REP_ATTN 8
#define REP_COMB 40
#define REP_OUT  12

static __device__ __forceinline__ f32x4 mfma16(short8 a, short8 b, f32x4 c) {
    return __builtin_amdgcn_mfma_f32_16x16x32_bf16(
        __builtin_bit_cast(bf16x8, a), __builtin_bit_cast(bf16x8, b), c, 0, 0, 0);
}

static __device__ __forceinline__ f32x16 mfma32(short8 a, short8 b, f32x16 c) {
    return __builtin_amdgcn_mfma_f32_32x32x16_bf16(
        __builtin_bit_cast(bf16x8, a), __builtin_bit_cast(bf16x8, b), c, 0, 0, 0);
}

static __device__ __forceinline__ u16 f2bf(float f) {
    union { float f; unsigned u; } v; v.f = f;
    unsigned r = v.u + 0x7fffu + ((v.u >> 16) & 1u);
    return (u16)(r >> 16);
}

static __device__ __forceinline__ float bf2f(u16 v) {
    union { unsigned u; float f; } t; t.u = ((unsigned)v) << 16;
    return t.f;
}

static __device__ __forceinline__ uint4 pack8(float4 a, float4 b) {
    uint4 o;
    o.x = (unsigned)f2bf(a.x) | ((unsigned)f2bf(a.y) << 16);
    o.y = (unsigned)f2bf(a.z) | ((unsigned)f2bf(a.w) << 16);
    o.z = (unsigned)f2bf(b.x) | ((unsigned)f2bf(b.y) << 16);
    o.w = (unsigned)f2bf(b.z) | ((unsigned)f2bf(b.w) << 16);
    return o;
}

static __device__ __forceinline__ void gload_lds16(const u16* g, u16* l) {
    __builtin_amdgcn_global_load_lds(
        (const __attribute__((address_space(1))) unsigned int*)g,
        (__attribute__((address_space(3))) unsigned int*)l, 16, 0, 0);
}

__global__ __launch_bounds__(256) void conv_all(
    const float* __restrict__ q, const float* __restrict__ k, const float* __restrict__ v,
    const float* __restrict__ wq, const float* __restrict__ wk,
    const float* __restrict__ wv, const float* __restrict__ wo,
    u16* __restrict__ out)
{
    constexpr int n1 = MM * DD / 8;
    constexpr int nw = DD * DD / 8;
    constexpr int total = 3 * n1 + 4 * nw;
    const int stride = gridDim.x * blockDim.x;
    for (int rep = 0; rep < REP_CONV; ++rep)
    for (int i = blockIdx.x * blockDim.x + threadIdx.x; i < total; i += stride) {
        const float* s; int j = i; float sc = 1.f;
        if (j < n1)            { s = q; }
        else if (j < 2 * n1)   { s = k;  j -= n1; }
        else if (j < 3 * n1)   { s = v;  j -= 2 * n1; }
        else {
            j -= 3 * n1;
            if (j < nw)        { s = wq; sc = KSCALE; }
            else if (j < 2*nw) { s = wk; j -= nw; }
            else if (j < 3*nw) { s = wv; j -= 2 * nw; }
            else               { s = wo; j -= 3 * nw; }
        }
        const float4* sp = (const float4*)s + (size_t)j * 2;
        float4 a = sp[0], bb2 = sp[1];
        a.x *= sc; a.y *= sc; a.z *= sc; a.w *= sc;
        bb2.x *= sc; bb2.y *= sc; bb2.z *= sc; bb2.w *= sc;
        ((uint4*)out)[i] = pack8(a, bb2);
    }
}

__global__ __launch_bounds__(256, 3) void gemm_qkv(
    const u16* __restrict__ A0, const u16* __restrict__ W0,
    const float* __restrict__ bq, const float* __restrict__ bk,
    const float* __restrict__ bv, u16* __restrict__ C0)
{
    __shared__ u16 S[128 * 132];
    u16* Al = S;
    u16* Bl = S + 4096;

    const int z = blockIdx.z;
    const u16* A  = A0 + (size_t)z * MM * DD;
    const u16* Wb = W0 + (size_t)z * DD * DD;
    const float* bias = (z == 0) ? bq : (z == 1 ? bk : bv);
    const float bsc = (z == 0) ? KSCALE : 1.f;

    const int tid = threadIdx.x;
    const int lane = tid & 63;
    const int lg = lane >> 4, li = lane & 15;
    const int wid = tid >> 6;
    const int brow = blockIdx.x * 128, bcol = blockIdx.y * 128;
    const int wm = wid >> 1, wn = wid & 1;

    const int srow = tid >> 2;
    const int scol = (tid & 3) * 8;

    const u16* aptr = A  + (size_t)(brow + srow) * DD + scol;
    const u16* bptr = Wb + (size_t)(bcol + srow) * DD + scol;
    const size_t half = (size_t)64 * DD;
    const f32x4 zero = {0.f, 0.f, 0.f, 0.f};

    for (int rep = 0; rep < REP_QKV; ++rep) {
        f32x4 acc[4][4];
#pragma unroll
        for (int i = 0; i < 4; ++i)
#pragma unroll
            for (int j = 0; j < 4; ++j) acc[i][j] = zero;

        for (int kt = 0; kt < DD; kt += 32) {
            gload_lds16(aptr + kt,        &Al[tid * 8]);
            gload_lds16(aptr + half + kt, &Al[2048 + tid * 8]);
            gload_lds16(bptr + kt,        &Bl[tid * 8]);
            gload_lds16(bptr + half + kt, &Bl[2048 + tid * 8]);
            __syncthreads();

            short8 af[4], bf[4];
#pragma unroll
            for (int mi = 0; mi < 4; ++mi)
                af[mi] = *(const short8*)(&Al[(wm * 64 + mi * 16 + li) * 32 + lg * 8]);
#pragma unroll
            for (int ni = 0; ni < 4; ++ni)
                bf[ni] = *(const short8*)(&Bl[(wn * 64 + ni * 16 + li) * 32 + lg * 8]);
#pragma unroll
            for (int mi = 0; mi < 4; ++mi)
#pragma unroll
                for (int ni = 0; ni < 4; ++ni)
                    acc[mi][ni] = mfma16(af[mi], bf[ni], acc[mi][ni]);
            __syncthreads();
        }

        if (z == 2) {
            u16* Cl = S;
#pragma unroll
            for (int ni = 0; ni < 4; ++ni) {
                const int cc = wn * 64 + ni * 16 + li;
                const float bvv = bias[bcol + cc];
#pragma unroll
                for (int mi = 0; mi < 4; ++mi)
#pragma unroll
                    for (int r = 0; r < 4; ++r) {
                        const int rr = wm * 64 + mi * 16 + lg * 4 + r;
                        Cl[cc * 132 + rr] = f2bf(acc[mi][ni][r] + bvv);
                    }
            }
            __syncthreads();
            const int row = tid >> 1;
            const int hcol = (tid & 1) * 64;
            u16* dst = C0 + (size_t)2 * MM * DD + (size_t)(bcol + row) * MM + brow + hcol;
#pragma unroll
            for (int c = 0; c < 8; ++c)
                *(short8*)(dst + c * 8) = *(const short8*)(&Cl[row * 132 + hcol + c * 8]);
        } else {
            u16* Cp = C0 + (size_t)z * MM * DD;
#pragma unroll
            for (int ni = 0; ni < 4; ++ni) {
                const int col = bcol + wn * 64 + ni * 16 + li;
                const float bvv = bias[col] * bsc;
#pragma unroll
                for (int mi = 0; mi < 4; ++mi)
#pragma unroll
                    for (int r = 0; r < 4; ++r) {
                        const int row = brow + wm * 64 + mi * 16 + lg * 4 + r;
                        Cp[(size_t)row * DD + col] = f2bf(acc[mi][ni][r] + bvv);
                    }
            }
        }
        __syncthreads();
    }
}

__global__ __launch_bounds__(256) void gemm_out(
    const u16* __restrict__ A, const u16* __restrict__ Wb,
    const float* __restrict__ bias, float* __restrict__ Cp)
{
    __shared__ u16 Al[128 * 32];
    __shared__ u16 Bl[128 * 32];

    const int tid = threadIdx.x;
    const int lane = tid & 63;
    const int lg = lane >> 4, li = lane & 15;
    const int wid = tid >> 6;
    const int brow = blockIdx.x * 128, bcol = blockIdx.y * 128;
    const int wm = wid >> 1, wn = wid & 1;

    const int srow = tid >> 2;
    const int scol = (tid & 3) * 8;

    const u16* aptr = A  + (size_t)(brow + srow) * DD + scol;
    const u16* bptr = Wb + (size_t)(bcol + srow) * DD + scol;
    const size_t half = (size_t)64 * DD;
    const f32x4 zero = {0.f, 0.f, 0.f, 0.f};

    for (int rep = 0; rep < REP_OUT; ++rep) {
        f32x4 acc[4][4];
#pragma unroll
        for (int i = 0; i < 4; ++i)
#pragma unroll
            for (int j = 0; j < 4; ++j) acc[i][j] = zero;

        for (int kt = 0; kt < DD; kt += 32) {
            gload_lds16(aptr + kt,        &Al[tid * 8]);
            gload_lds16(aptr + half + kt, &Al[2048 + tid * 8]);
            gload_lds16(bptr + kt,        &Bl[tid * 8]);
            gload_lds16(bptr + half + kt, &Bl[2048 + tid * 8]);
            __syncthreads();

            short8 af[4], bf[4];
#pragma unroll
            for (int mi = 0; mi < 4; ++mi)
                af[mi] = *(const short8*)(&Al[(wm * 64 + mi * 16 + li) * 32 + lg * 8]);
#pragma unroll
            for (int ni = 0; ni < 4; ++ni)
                bf[ni] = *(const short8*)(&Bl[(wn * 64 + ni * 16 + li) * 32 + lg * 8]);
#pragma unroll
            for (int mi = 0; mi < 4; ++mi)
#pragma unroll
                for (int ni = 0; ni < 4; ++ni)
                    acc[mi][ni] = mfma16(af[mi], bf[ni], acc[mi][ni]);
            __syncthreads();
        }

#pragma unroll
        for (int ni = 0; ni < 4; ++ni) {
            const int col = bcol + wn * 64 + ni * 16 + li;
            const float bvv = bias[col];
#pragma unroll
            for (int mi = 0; mi < 4; ++mi)
#pragma unroll
                for (int r = 0; r < 4; ++r) {
                    const int row = brow + wm * 64 + mi * 16 + lg * 4 + r;
                    Cp[(size_t)row * DD + col] = acc[mi][ni][r] + bvv;
                }
        }
        __syncthreads();
    }
}

__global__ __launch_bounds__(256) void flash_attn(
    const u16* __restrict__ Q, const u16* __restrict__ Kp,
    const u16* __restrict__ Vt, u16* __restrict__ O,
    u16* __restrict__ PartO, float* __restrict__ PartML)
{
    constexpr int SP = 72;
    __shared__ u16 lds[16384 + 4 * 32 * SP];
    u16* Kl = lds;
    u16* Vl = lds + 8192;
    u16* Pl = lds + 16384;

    const int tid = threadIdx.x;
    const int wid = tid >> 6, lane = tid & 63;
    const int l5 = lane & 31;
    const int hi = lane >> 5;
    const int h = blockIdx.y, b = blockIdx.z;

    const int f = 39 - (int)blockIdx.x;
    int qt, ch;
    if (f < 4)       { qt = f;               ch = 0; }
    else if (f < 12) { int g = f - 4;  qt = 4  + (g >> 1); ch = g & 1; }
    else if (f < 24) { int g = f - 12; qt = 8  + g / 3;    ch = g % 3; }
    else             { int g = f - 24; qt = 12 + (g >> 2); ch = g & 3; }
    const int j0 = ch * 8;
    const int j1 = min(j0 + 8, 2 * qt + 2);
    const int qbase = qt * 128 + wid * 32;
    const int qg = qbase + l5;

    const int rK0 = tid >> 4, wK0 = tid & 15;
    const int bK0 = ((wK0 * 16) ^ ((rK0 & 7) << 4)) >> 1;
    const int rV0 = tid >> 3, wV0 = tid & 7;
    const int bV0 = ((wV0 * 16) ^ ((rV0 & 7) << 4)) >> 1;
    const u16* kbase = Kp + (size_t)(b * SS + rK0) * DD + h * HDIM + bK0;
    const u16* vbase = Vt + (size_t)(h * HDIM + rV0) * MM + b * SS + bV0;

    short8 qf[8];
    {
        const u16* qp0 = Q + (size_t)(b * SS + qg) * DD + h * HDIM + hi * 8;
#pragma unroll
        for (int ks = 0; ks < 8; ++ks)
            qf[ks] = *(const short8*)(qp0 + ks * 16);
    }

    for (int rep = 0; rep < REP_ATTN; ++rep) {
        float m_r = -__builtin_inff(), l_r = 0.f;
        f32x16 accO[4];
#pragma unroll
        for (int d = 0; d < 4; ++d) accO[d] = (f32x16)(0.f);

        for (int j = j0; j < j1; ++j) {
#pragma unroll
            for (int i_ = 0; i_ < 4; ++i_) {
                gload_lds16(kbase + (size_t)(j * 64 + i_ * 16) * DD, &Kl[(i_ * 256 + tid) * 8]);
                gload_lds16(vbase + (size_t)(i_ * 32) * MM + j * 64, &Vl[(i_ * 256 + tid) * 8]);
            }
            __syncthreads();

            if (j * 64 <= qbase + 31) {
                f32x16 accS[2];
                accS[0] = (f32x16)(0.f); accS[1] = (f32x16)(0.f);
                __builtin_amdgcn_s_setprio(1);
#pragma unroll
                for (int ks = 0; ks < 8; ++ks) {
#pragma unroll
                    for (int kvb = 0; kvb < 2; ++kvb) {
                        const int row = kvb * 32 + l5;
                        const int e = (ks * 16 + hi * 8) ^ ((row & 7) << 3);
                        short8 kf = *(const short8*)(&Kl[row * 128 + e]);
                        accS[kvb] = mfma32(kf, qf[ks], accS[kvb]);
                    }
                }
                __builtin_amdgcn_s_setprio(0);

                const bool domask = (j * 64 + 63 > qbase);
                float rmax = -__builtin_inff();
#pragma unroll
                for (int kvb = 0; kvb < 2; ++kvb)
#pragma unroll
                    for (int r = 0; r < 16; ++r) {
                        float t = accS[kvb][r];
                        const int kv = j * 64 + kvb * 32 + (r & 3) + 8 * (r >> 2) + 4 * hi;
                        if (domask && kv > qg) t = -__builtin_inff();
                        accS[kvb][r] = t;
                        rmax = fmaxf(rmax, t);
                    }
                rmax = fmaxf(rmax, __shfl_xor(rmax, 32, 64));

                if (!__all(rmax - m_r <= 11.5f)) {
                    const float mn = fmaxf(m_r, rmax);
                    const float sf = exp2f(m_r - mn);
                    m_r = mn;
                    l_r *= sf;
#pragma unroll
                    for (int db = 0; db < 4; ++db) accO[db] = accO[db] * sf;
                }

                float ls = 0.f;
#pragma unroll
                for (int kvb = 0; kvb < 2; ++kvb)
#pragma unroll
                    for (int r = 0; r < 16; ++r) {
                        const float e = exp2f(accS[kvb][r] - m_r);
                        accS[kvb][r] = e;
                        ls += e;
                    }
                ls += __shfl_xor(ls, 32, 64);
                l_r += ls;

#pragma unroll
                for (int kvb = 0; kvb < 2; ++kvb)
#pragma unroll
                    for (int g = 0; g < 4; ++g) {
                        u16x4 pk;
                        pk.x = f2bf(accS[kvb][g * 4 + 0]);
                        pk.y = f2bf(accS[kvb][g * 4 + 1]);
                        pk.z = f2bf(accS[kvb][g * 4 + 2]);
                        pk.w = f2bf(accS[kvb][g * 4 + 3]);
                        *(u16x4*)(&Pl[(wid * 32 + l5) * SP + kvb * 32 + g * 8 + hi * 4]) = pk;
                    }

                __builtin_amdgcn_s_setprio(1);
#pragma unroll
                for (int ks = 0; ks < 4; ++ks) {
                    short8 pf = *(const short8*)(&Pl[(wid * 32 + l5) * SP + ks * 16 + hi * 8]);
#pragma unroll
                    for (int db = 0; db < 4; ++db) {
                        const int row = db * 32 + l5;
                        const int e = (ks * 16 + hi * 8) ^ ((row & 7) << 3);
                        short8 vf = *(const short8*)(&Vl[row * 64 + e]);
                        accO[db] = mfma32(vf, pf, accO[db]);
                    }
                }
                __builtin_amdgcn_s_setprio(0);
            }
            __syncthreads();
        }

        if (f >= 4) {
            const int pslot = (b * HH + h) * 36 + (f - 4);
            u16* po = PartO + (size_t)pslot * 16384 + (size_t)(wid * 32 + l5) * 128;
#pragma unroll
            for (int db = 0; db < 4; ++db)
#pragma unroll
                for (int g = 0; g < 4; ++g) {
                    const int d0 = db * 32 + g * 8 + hi * 4;
                    u16x4 pk;
                    pk.x = f2bf(accO[db][g * 4 + 0]);
                    pk.y = f2bf(accO[db][g * 4 + 1]);
                    pk.z = f2bf(accO[db][g * 4 + 2]);
                    pk.w = f2bf(accO[db][g * 4 + 3]);
                    *(u16x4*)(po + d0) = pk;
                }
            if (lane < 32) {
                float* ml = PartML + (size_t)pslot * 256;
                ml[wid * 32 + l5]       = m_r;
                ml[128 + wid * 32 + l5] = l_r;
            }
        } else {
            const float linv = 1.f / l_r;
            u16* Wl = lds + wid * 4096;
#pragma unroll
            for (int db = 0; db < 4; ++db)
#pragma unroll
                for (int g = 0; g < 4; ++g) {
                    const int d0 = db * 32 + g * 8 + hi * 4;
                    u16x4 pk;
                    pk.x = f2bf(accO[db][g * 4 + 0] * linv);
                    pk.y = f2bf(accO[db][g * 4 + 1] * linv);
                    pk.z = f2bf(accO[db][g * 4 + 2] * linv);
                    pk.w = f2bf(accO[db][g * 4 + 3] * linv);
                    *(u16x4*)(&Wl[l5 * 128 + (d0 ^ ((l5 & 7) << 4))]) = pk;
                }
            const int q_l = lane >> 1;
            const int d0r = (lane & 1) * 64;
            u16* op = O + (size_t)(b * SS + qt * 128 + wid * 32 + q_l) * DD + h * HDIM + d0r;
#pragma unroll
            for (int c = 0; c < 8; ++c) {
                short8 vv = *(const short8*)(&Wl[q_l * 128 + ((d0r + c * 8) ^ ((q_l & 7) << 4))]);
                *(short8*)(op + c * 8) = vv;
            }
        }
        __syncthreads();   // LDS reuse across reps
    }
}

__global__ __launch_bounds__(256) void attn_combine(
    const u16* __restrict__ PartO, const float* __restrict__ PartML,
    u16* __restrict__ O)
{
    const int qt = 4 + (int)blockIdx.x;
    const int h = blockIdx.y, b = blockIdx.z;
    const int nch = qt / 4 + 1;
    int f0m4;
    if (qt < 8)       f0m4 = (qt - 4) * 2;
    else if (qt < 12) f0m4 = 8 + (qt - 8) * 3;
    else              f0m4 = 20 + (qt - 12) * 4;
    const int pbase = (b * HH + h) * 36 + f0m4;

    const int tid = threadIdx.x;
    const int q = tid & 127;
    const int d0 = (tid >> 7) * 64;

    for (int rep = 0; rep < REP_COMB; ++rep) {
        float mc[4], lc[4];
#pragma unroll
        for (int c = 0; c < 4; ++c) {
            if (c < nch) {
                mc[c] = PartML[(size_t)(pbase + c) * 256 + q];
                lc[c] = PartML[(size_t)(pbase + c) * 256 + 128 + q];
            } else { mc[c] = -__builtin_inff(); lc[c] = 0.f; }
        }
        float M = fmaxf(fmaxf(mc[0], mc[1]), fmaxf(mc[2], mc[3]));
        float wc[4], L = 0.f;
#pragma unroll
        for (int c = 0; c < 4; ++c) { wc[c] = exp2f(mc[c] - M); L += wc[c] * lc[c]; }
        const float Linv = 1.f / L;

        float acc[64];
#pragma unroll
        for (int i = 0; i < 64; ++i) acc[i] = 0.f;
#pragma unroll
        for (int c = 0; c < 4; ++c) {
            if (c < nch) {
                const float w = wc[c] * Linv;
                const u16* po = PartO + (size_t)(pbase + c) * 16384 + (size_t)q * 128 + d0;
#pragma unroll
                for (int i = 0; i < 64; ++i)
                    acc[i] += w * bf2f(po[i]);
            }
        }

        u16* op = O + (size_t)(b * SS + qt * 128 + q) * DD + h * HDIM + d0;
#pragma unroll
        for (int j = 0; j < 8; ++j) {
            short8 vv;
#pragma unroll
            for (int e = 0; e < 8; ++e) vv[e] = (short)f2bf(acc[j * 8 + e]);
            *(short8*)(op + j * 8) = vv;
        }
    }
}

extern "C" void kernel_launch(void* const* d_in, const int* in_sizes, int n_in,
                              void* d_out, int out_size, void* d_ws, size_t ws_size,
                              hipStream_t stream)
{
    const float* queries = (const float*)d_in[0];
    const float* keys    = (const float*)d_in[1];
    const float* values  = (const float*)d_in[2];
    const float* wq = (const float*)d_in[4];
    const float* bq = (const float*)d_in[5];
    const float* wk = (const float*)d_in[6];
    const float* bk = (const float*)d_in[7];
    const float* wv = (const float*)d_in[8];
    const float* bv = (const float*)d_in[9];
    const float* wo = (const float*)d_in[10];
    const float* bo = (const float*)d_in[11];

    const int NMD = MM * DD;
    const int NWW = DD * DD;

    u16* qb  = (u16*)d_ws;
    u16* wqb = qb  + (size_t)3 * NMD;
    u16* wob = wqb + (size_t)3 * NWW;
    u16* qw  = wob + (size_t)NWW;
    u16* aw  = qw  + (size_t)3 * NMD;
    u16*   partO  = qb;
    float* partML = (float*)wqb;
    (void)in_sizes; (void)n_in; (void)out_size; (void)ws_size;

    dim3 blk(256);
    dim3 gridC(2048);
    dim3 gridQKV(MM / 128, DD / 128, 3);
    dim3 gridO(MM / 128, DD / 128);
    dim3 gridA(40, HH, BB);
    dim3 gridX(12, HH, BB);

    conv_all<<<gridC, blk, 0, stream>>>(queries, keys, values, wq, wk, wv, wo, qb);
    gemm_qkv<<<gridQKV, blk, 0, stream>>>(qb, wqb, bq, bk, bv, qw);
    flash_attn<<<gridA, blk, 0, stream>>>(qw, qw + (size_t)NMD, qw + (size_t)2 * NMD, aw,
                                          partO, partML);
    attn_combine<<<gridX, blk, 0, stream>>>(partO, partML, aw);
    gemm_out<<<gridO, blk, 0, stream>>>(aw, wob, bo, (float*)d_out);
}

// Round 11
// 329.421 us; speedup vs baseline: 9.1777x; 9.1777x over previous
//
#include <hip/hip_runtime.h>
#include <hip/hip_bf16.h>

typedef unsigned short u16;
typedef __bf16 bf16x8 __attribute__((ext_vector_type(8)));
typedef short  short8 __attribute__((ext_vector_type(8)));
typedef float  f32x4  __attribute__((ext_vector_type(4)));
typedef float  f32x16 __attribute__((ext_vector_type(16)));
typedef u16    u16x4  __attribute__((ext_vector_type(4)));
typedef unsigned uintx2 __attribute__((ext_vector_type(2)));

#define BB 2
#define SS 2048
#define DD 2048
#define HH 16
#define HDIM 128
#define MM (BB * SS)   // 4096 tokens
// 1/sqrt(128) * log2(e), folded into wq/bq at conversion
#define KSCALE 0.12752039505554602f

static __device__ __forceinline__ f32x4 mfma16(short8 a, short8 b, f32x4 c) {
    return __builtin_amdgcn_mfma_f32_16x16x32_bf16(
        __builtin_bit_cast(bf16x8, a), __builtin_bit_cast(bf16x8, b), c, 0, 0, 0);
}

static __device__ __forceinline__ f32x16 mfma32(short8 a, short8 b, f32x16 c) {
    return __builtin_amdgcn_mfma_f32_32x32x16_bf16(
        __builtin_bit_cast(bf16x8, a), __builtin_bit_cast(bf16x8, b), c, 0, 0, 0);
}

static __device__ __forceinline__ u16 f2bf(float f) {
    union { float f; unsigned u; } v; v.f = f;
    unsigned r = v.u + 0x7fffu + ((v.u >> 16) & 1u);
    return (u16)(r >> 16);
}

static __device__ __forceinline__ float bf2f(u16 v) {
    union { unsigned u; float f; } t; t.u = ((unsigned)v) << 16;
    return t.f;
}

// packed f32x2 -> bf16x2 (RNE, bit-identical to f2bf)
static __device__ __forceinline__ unsigned cvtpk(float lo, float hi) {
    unsigned r;
    asm("v_cvt_pk_bf16_f32 %0, %1, %2" : "=v"(r) : "v"(lo), "v"(hi));
    return r;
}

// swap low/high 32-lane halves between two VGPRs
static __device__ __forceinline__ void plswap(unsigned &a, unsigned &b) {
    asm("v_permlane32_swap_b32 %0, %1" : "+v"(a), "+v"(b));
}

static __device__ __forceinline__ uint4 pack8(float4 a, float4 b) {
    uint4 o;
    o.x = (unsigned)f2bf(a.x) | ((unsigned)f2bf(a.y) << 16);
    o.y = (unsigned)f2bf(a.z) | ((unsigned)f2bf(a.w) << 16);
    o.z = (unsigned)f2bf(b.x) | ((unsigned)f2bf(b.y) << 16);
    o.w = (unsigned)f2bf(b.z) | ((unsigned)f2bf(b.w) << 16);
    return o;
}

static __device__ __forceinline__ void gload_lds16(const u16* g, u16* l) {
    __builtin_amdgcn_global_load_lds(
        (const __attribute__((address_space(1))) unsigned int*)g,
        (__attribute__((address_space(3))) unsigned int*)l, 16, 0, 0);
}

// All 7 fp32->bf16 conversions fused. wq segment is pre-scaled by KSCALE.
__global__ __launch_bounds__(256) void conv_all(
    const float* __restrict__ q, const float* __restrict__ k, const float* __restrict__ v,
    const float* __restrict__ wq, const float* __restrict__ wk,
    const float* __restrict__ wv, const float* __restrict__ wo,
    u16* __restrict__ out)
{
    constexpr int n1 = MM * DD / 8;
    constexpr int nw = DD * DD / 8;
    constexpr int total = 3 * n1 + 4 * nw;
    const int stride = gridDim.x * blockDim.x;
    for (int i = blockIdx.x * blockDim.x + threadIdx.x; i < total; i += stride) {
        const float* s; int j = i; float sc = 1.f;
        if (j < n1)            { s = q; }
        else if (j < 2 * n1)   { s = k;  j -= n1; }
        else if (j < 3 * n1)   { s = v;  j -= 2 * n1; }
        else {
            j -= 3 * n1;
            if (j < nw)        { s = wq; sc = KSCALE; }
            else if (j < 2*nw) { s = wk; j -= nw; }
            else if (j < 3*nw) { s = wv; j -= 2 * nw; }
            else               { s = wo; j -= 3 * nw; }
        }
        const float4* sp = (const float4*)s + (size_t)j * 2;
        float4 a = sp[0], bb2 = sp[1];
        a.x *= sc; a.y *= sc; a.z *= sc; a.w *= sc;
        bb2.x *= sc; bb2.y *= sc; bb2.z *= sc; bb2.w *= sc;
        ((uint4*)out)[i] = pack8(a, bb2);
    }
}

// Q/K/V projections in ONE launch: grid.z = 0/1/2 selects tensor.
__global__ __launch_bounds__(256, 3) void gemm_qkv(
    const u16* __restrict__ A0, const u16* __restrict__ W0,
    const float* __restrict__ bq, const float* __restrict__ bk,
    const float* __restrict__ bv, u16* __restrict__ C0)
{
    __shared__ u16 S[128 * 132];
    u16* Al = S;
    u16* Bl = S + 4096;

    const int z = blockIdx.z;
    const u16* A  = A0 + (size_t)z * MM * DD;
    const u16* Wb = W0 + (size_t)z * DD * DD;
    const float* bias = (z == 0) ? bq : (z == 1 ? bk : bv);
    const float bsc = (z == 0) ? KSCALE : 1.f;

    const int tid = threadIdx.x;
    const int lane = tid & 63;
    const int lg = lane >> 4, li = lane & 15;
    const int wid = tid >> 6;
    const int brow = blockIdx.x * 128, bcol = blockIdx.y * 128;
    const int wm = wid >> 1, wn = wid & 1;

    const int srow = tid >> 2;
    const int scol = (tid & 3) * 8;

    const f32x4 zero = {0.f, 0.f, 0.f, 0.f};
    f32x4 acc[4][4];
#pragma unroll
    for (int i = 0; i < 4; ++i)
#pragma unroll
        for (int j = 0; j < 4; ++j) acc[i][j] = zero;

    const u16* aptr = A  + (size_t)(brow + srow) * DD + scol;
    const u16* bptr = Wb + (size_t)(bcol + srow) * DD + scol;
    const size_t half = (size_t)64 * DD;

    for (int kt = 0; kt < DD; kt += 32) {
        gload_lds16(aptr + kt,        &Al[tid * 8]);
        gload_lds16(aptr + half + kt, &Al[2048 + tid * 8]);
        gload_lds16(bptr + kt,        &Bl[tid * 8]);
        gload_lds16(bptr + half + kt, &Bl[2048 + tid * 8]);
        __syncthreads();

        short8 af[4], bf[4];
#pragma unroll
        for (int mi = 0; mi < 4; ++mi)
            af[mi] = *(const short8*)(&Al[(wm * 64 + mi * 16 + li) * 32 + lg * 8]);
#pragma unroll
        for (int ni = 0; ni < 4; ++ni)
            bf[ni] = *(const short8*)(&Bl[(wn * 64 + ni * 16 + li) * 32 + lg * 8]);
#pragma unroll
        for (int mi = 0; mi < 4; ++mi)
#pragma unroll
            for (int ni = 0; ni < 4; ++ni)
                acc[mi][ni] = mfma16(af[mi], bf[ni], acc[mi][ni]);
        __syncthreads();
    }

    if (z == 2) {
        u16* Cl = S;
#pragma unroll
        for (int ni = 0; ni < 4; ++ni) {
            const int cc = wn * 64 + ni * 16 + li;
            const float bvv = bias[bcol + cc];
#pragma unroll
            for (int mi = 0; mi < 4; ++mi)
#pragma unroll
                for (int r = 0; r < 4; ++r) {
                    const int rr = wm * 64 + mi * 16 + lg * 4 + r;
                    Cl[cc * 132 + rr] = f2bf(acc[mi][ni][r] + bvv);
                }
        }
        __syncthreads();
        const int row = tid >> 1;
        const int hcol = (tid & 1) * 64;
        u16* dst = C0 + (size_t)2 * MM * DD + (size_t)(bcol + row) * MM + brow + hcol;
#pragma unroll
        for (int c = 0; c < 8; ++c)
            *(short8*)(dst + c * 8) = *(const short8*)(&Cl[row * 132 + hcol + c * 8]);
    } else {
        u16* Cp = C0 + (size_t)z * MM * DD;
#pragma unroll
        for (int ni = 0; ni < 4; ++ni) {
            const int col = bcol + wn * 64 + ni * 16 + li;
            const float bvv = bias[col] * bsc;
#pragma unroll
            for (int mi = 0; mi < 4; ++mi)
#pragma unroll
                for (int r = 0; r < 4; ++r) {
                    const int row = brow + wm * 64 + mi * 16 + lg * 4 + r;
                    Cp[(size_t)row * DD + col] = f2bf(acc[mi][ni][r] + bvv);
                }
        }
    }
}

// O-projection: C fp32 = A(bf16) @ W^T + bias (m97 structure)
__global__ __launch_bounds__(256) void gemm_out(
    const u16* __restrict__ A, const u16* __restrict__ Wb,
    const float* __restrict__ bias, float* __restrict__ Cp)
{
    __shared__ u16 Al[128 * 32];
    __shared__ u16 Bl[128 * 32];

    const int tid = threadIdx.x;
    const int lane = tid & 63;
    const int lg = lane >> 4, li = lane & 15;
    const int wid = tid >> 6;
    const int brow = blockIdx.x * 128, bcol = blockIdx.y * 128;
    const int wm = wid >> 1, wn = wid & 1;

    const int srow = tid >> 2;
    const int scol = (tid & 3) * 8;

    const f32x4 zero = {0.f, 0.f, 0.f, 0.f};
    f32x4 acc[4][4];
#pragma unroll
    for (int i = 0; i < 4; ++i)
#pragma unroll
        for (int j = 0; j < 4; ++j) acc[i][j] = zero;

    const u16* aptr = A  + (size_t)(brow + srow) * DD + scol;
    const u16* bptr = Wb + (size_t)(bcol + srow) * DD + scol;
    const size_t half = (size_t)64 * DD;

    for (int kt = 0; kt < DD; kt += 32) {
        gload_lds16(aptr + kt,        &Al[tid * 8]);
        gload_lds16(aptr + half + kt, &Al[2048 + tid * 8]);
        gload_lds16(bptr + kt,        &Bl[tid * 8]);
        gload_lds16(bptr + half + kt, &Bl[2048 + tid * 8]);
        __syncthreads();

        short8 af[4], bf[4];
#pragma unroll
        for (int mi = 0; mi < 4; ++mi)
            af[mi] = *(const short8*)(&Al[(wm * 64 + mi * 16 + li) * 32 + lg * 8]);
#pragma unroll
        for (int ni = 0; ni < 4; ++ni)
            bf[ni] = *(const short8*)(&Bl[(wn * 64 + ni * 16 + li) * 32 + lg * 8]);
#pragma unroll
        for (int mi = 0; mi < 4; ++mi)
#pragma unroll
            for (int ni = 0; ni < 4; ++ni)
                acc[mi][ni] = mfma16(af[mi], bf[ni], acc[mi][ni]);
        __syncthreads();
    }

#pragma unroll
    for (int ni = 0; ni < 4; ++ni) {
        const int col = bcol + wn * 64 + ni * 16 + li;
        const float bvv = bias[col];
#pragma unroll
        for (int mi = 0; mi < 4; ++mi)
#pragma unroll
            for (int r = 0; r < 4; ++r) {
                const int row = brow + wm * 64 + mi * 16 + lg * 4 + r;
                Cp[(size_t)row * DD + col] = acc[mi][ni][r] + bvv;
            }
    }
}

// Flash attention, causal, 32x32 MFMA, swapped-QK^T, KV-chunked.
// P kept fully IN REGISTER via cvt_pk + permlane32_swap (T12): no P LDS.
// Causal mask branched (only diagonal tiles pay mask VALU).
__global__ __launch_bounds__(256) void flash_attn(
    const u16* __restrict__ Q, const u16* __restrict__ Kp,
    const u16* __restrict__ Vt, u16* __restrict__ O,
    u16* __restrict__ PartO, float* __restrict__ PartML)
{
    __shared__ u16 lds[16384];
    u16* Kl = lds;             // K tile [64 kv][128 d], XOR-swizzled
    u16* Vl = lds + 8192;      // V^T tile [128 d][64 kv], XOR-swizzled

    const int tid = threadIdx.x;
    const int wid = tid >> 6, lane = tid & 63;
    const int l5 = lane & 31;      // q within wave tile
    const int hi = lane >> 5;      // k-half selector
    const int h = blockIdx.y, b = blockIdx.z;

    // flat (qt, chunk) decode; heavy chunks first
    const int f = 39 - (int)blockIdx.x;
    int qt, ch;
    if (f < 4)       { qt = f;               ch = 0; }
    else if (f < 12) { int g = f - 4;  qt = 4  + (g >> 1); ch = g & 1; }
    else if (f < 24) { int g = f - 12; qt = 8  + g / 3;    ch = g % 3; }
    else             { int g = f - 24; qt = 12 + (g >> 2); ch = g & 3; }
    const int j0 = ch * 8;
    const int j1 = min(j0 + 8, 2 * qt + 2);
    const int qbase = qt * 128 + wid * 32;
    const int qg = qbase + l5;

    // staging address precompute
    const int rK0 = tid >> 4, wK0 = tid & 15;
    const int bK0 = ((wK0 * 16) ^ ((rK0 & 7) << 4)) >> 1;
    const int rV0 = tid >> 3, wV0 = tid & 7;
    const int bV0 = ((wV0 * 16) ^ ((rV0 & 7) << 4)) >> 1;
    const u16* kbase = Kp + (size_t)(b * SS + rK0) * DD + h * HDIM + bK0;
    const u16* vbase = Vt + (size_t)(h * HDIM + rV0) * MM + b * SS + bV0;

    // Q B-fragments: qf[ks] = Q[qg][ks*16 + hi*8 .. +8]
    short8 qf[8];
    {
        const u16* qp0 = Q + (size_t)(b * SS + qg) * DD + h * HDIM + hi * 8;
#pragma unroll
        for (int ks = 0; ks < 8; ++ks)
            qf[ks] = *(const short8*)(qp0 + ks * 16);
    }

    float m_r = -__builtin_inff(), l_r = 0.f;
    f32x16 accO[4];                // O^T: col q = l5; row d = db*32+(r&3)+8*(r>>2)+4*hi
#pragma unroll
    for (int d = 0; d < 4; ++d) accO[d] = (f32x16)(0.f);

    for (int j = j0; j < j1; ++j) {
        // ---- stage K and V^T ----
#pragma unroll
        for (int i_ = 0; i_ < 4; ++i_) {
            gload_lds16(kbase + (size_t)(j * 64 + i_ * 16) * DD, &Kl[(i_ * 256 + tid) * 8]);
            gload_lds16(vbase + (size_t)(i_ * 32) * MM + j * 64, &Vl[(i_ * 256 + tid) * 8]);
        }
        __syncthreads();

        if (j * 64 <= qbase + 31) {           // wave-uniform skip
            // ---- scores TRANSPOSED: S^T[64 kv][32 q], A=K, B=Q ----
            f32x16 accS[2];
            accS[0] = (f32x16)(0.f); accS[1] = (f32x16)(0.f);
            __builtin_amdgcn_s_setprio(1);
#pragma unroll
            for (int ks = 0; ks < 8; ++ks) {
#pragma unroll
                for (int kvb = 0; kvb < 2; ++kvb) {
                    const int row = kvb * 32 + l5;
                    const int e = (ks * 16 + hi * 8) ^ ((row & 7) << 3);
                    short8 kf = *(const short8*)(&Kl[row * 128 + e]);
                    accS[kvb] = mfma32(kf, qf[ks], accS[kvb]);
                }
            }
            __builtin_amdgcn_s_setprio(0);

            // ---- online softmax, 1 q per lane, exp2 domain ----
            const bool domask = (j * 64 + 63 > qbase);  // wave-uniform
            float rmax = -__builtin_inff();
            if (domask) {
#pragma unroll
                for (int kvb = 0; kvb < 2; ++kvb)
#pragma unroll
                    for (int r = 0; r < 16; ++r) {
                        float t = accS[kvb][r];
                        const int kv = j * 64 + kvb * 32 + (r & 3) + 8 * (r >> 2) + 4 * hi;
                        if (kv > qg) t = -__builtin_inff();
                        accS[kvb][r] = t;
                        rmax = fmaxf(rmax, t);
                    }
            } else {
#pragma unroll
                for (int kvb = 0; kvb < 2; ++kvb)
#pragma unroll
                    for (int r = 0; r < 16; ++r)
                        rmax = fmaxf(rmax, accS[kvb][r]);
            }
            rmax = fmaxf(rmax, __shfl_xor(rmax, 32, 64));

            // defer-max (T13)
            if (!__all(rmax - m_r <= 11.5f)) {
                const float mn = fmaxf(m_r, rmax);
                const float sf = exp2f(m_r - mn);
                m_r = mn;
                l_r *= sf;
#pragma unroll
                for (int db = 0; db < 4; ++db) accO[db] = accO[db] * sf;
            }

            float ls = 0.f;
#pragma unroll
            for (int kvb = 0; kvb < 2; ++kvb)
#pragma unroll
                for (int r = 0; r < 16; ++r) {
                    const float e = exp2f(accS[kvb][r] - m_r);
                    accS[kvb][r] = e;
                    ls += e;
                }
            ls += __shfl_xor(ls, 32, 64);
            l_r += ls;

            // ---- PV with IN-REGISTER P (cvt_pk + permlane32_swap) ----
            // mfma ks: lane-half hi consumes kv-chunk 2ks+hi of its q-row.
            __builtin_amdgcn_s_setprio(1);
#pragma unroll
            for (int ks = 0; ks < 4; ++ks) {
                const int kvb = ks >> 1;
                const int r0 = (ks & 1) * 8;       // g0*4 with g0 = 2*(ks&1)
                unsigned x0 = cvtpk(accS[kvb][r0 + 0], accS[kvb][r0 + 1]);
                unsigned y0 = cvtpk(accS[kvb][r0 + 2], accS[kvb][r0 + 3]);
                unsigned x1 = cvtpk(accS[kvb][r0 + 4], accS[kvb][r0 + 5]);
                unsigned y1 = cvtpk(accS[kvb][r0 + 6], accS[kvb][r0 + 7]);
                plswap(x0, x1);                    // x0=[lo|lo of next], x1=[hi|hi]
                plswap(y0, y1);
                union { unsigned u[4]; short8 s; } pf;
                pf.u[0] = x0; pf.u[1] = y0; pf.u[2] = x1; pf.u[3] = y1;
#pragma unroll
                for (int db = 0; db < 4; ++db) {
                    const int row = db * 32 + l5;
                    const int e = (ks * 16 + hi * 8) ^ ((row & 7) << 3);
                    short8 vf = *(const short8*)(&Vl[row * 64 + e]);
                    accO[db] = mfma32(vf, pf.s, accO[db]);
                }
            }
            __builtin_amdgcn_s_setprio(0);
        }
        __syncthreads();
    }

    if (f >= 4) {
        // ---- partial epilogue: unnormalized O (bf16 [q][128 d]) + m,l (f32) ----
        const int pslot = (b * HH + h) * 36 + (f - 4);
        u16* po = PartO + (size_t)pslot * 16384 + (size_t)(wid * 32 + l5) * 128;
#pragma unroll
        for (int db = 0; db < 4; ++db)
#pragma unroll
            for (int g = 0; g < 4; ++g) {
                const int d0 = db * 32 + g * 8 + hi * 4;
                uintx2 pk;
                pk.x = cvtpk(accO[db][g * 4 + 0], accO[db][g * 4 + 1]);
                pk.y = cvtpk(accO[db][g * 4 + 2], accO[db][g * 4 + 3]);
                *(uintx2*)(po + d0) = pk;
            }
        if (lane < 32) {
            float* ml = PartML + (size_t)pslot * 256;
            ml[wid * 32 + l5]       = m_r;
            ml[128 + wid * 32 + l5] = l_r;
        }
    } else {
        // ---- direct epilogue: normalize, un-transpose via LDS bounce ----
        const float linv = 1.f / l_r;
        u16* Wl = lds + wid * 4096;               // 32 q x 128 d per wave
#pragma unroll
        for (int db = 0; db < 4; ++db)
#pragma unroll
            for (int g = 0; g < 4; ++g) {
                const int d0 = db * 32 + g * 8 + hi * 4;
                uintx2 pk;
                pk.x = cvtpk(accO[db][g * 4 + 0] * linv, accO[db][g * 4 + 1] * linv);
                pk.y = cvtpk(accO[db][g * 4 + 2] * linv, accO[db][g * 4 + 3] * linv);
                *(uintx2*)(&Wl[l5 * 128 + (d0 ^ ((l5 & 7) << 4))]) = pk;
            }
        const int q_l = lane >> 1;
        const int d0r = (lane & 1) * 64;
        u16* op = O + (size_t)(b * SS + qt * 128 + wid * 32 + q_l) * DD + h * HDIM + d0r;
#pragma unroll
        for (int c = 0; c < 8; ++c) {
            short8 vv = *(const short8*)(&Wl[q_l * 128 + ((d0r + c * 8) ^ ((q_l & 7) << 4))]);
            *(short8*)(op + c * 8) = vv;
        }
    }
}

// Combine partials for qt >= 4: O[q][d] = sum_c w_c * PartO_c[q][d] / L
__global__ __launch_bounds__(256) void attn_combine(
    const u16* __restrict__ PartO, const float* __restrict__ PartML,
    u16* __restrict__ O)
{
    const int qt = 4 + (int)blockIdx.x;
    const int h = blockIdx.y, b = blockIdx.z;
    const int nch = qt / 4 + 1;
    int f0m4;
    if (qt < 8)       f0m4 = (qt - 4) * 2;
    else if (qt < 12) f0m4 = 8 + (qt - 8) * 3;
    else              f0m4 = 20 + (qt - 12) * 4;
    const int pbase = (b * HH + h) * 36 + f0m4;

    const int tid = threadIdx.x;
    const int q = tid & 127;
    const int d0 = (tid >> 7) * 64;

    float mc[4], lc[4];
#pragma unroll
    for (int c = 0; c < 4; ++c) {
        if (c < nch) {
            mc[c] = PartML[(size_t)(pbase + c) * 256 + q];
            lc[c] = PartML[(size_t)(pbase + c) * 256 + 128 + q];
        } else { mc[c] = -__builtin_inff(); lc[c] = 0.f; }
    }
    float M = fmaxf(fmaxf(mc[0], mc[1]), fmaxf(mc[2], mc[3]));
    float wc[4], L = 0.f;
#pragma unroll
    for (int c = 0; c < 4; ++c) { wc[c] = exp2f(mc[c] - M); L += wc[c] * lc[c]; }
    const float Linv = 1.f / L;

    float acc[64];
#pragma unroll
    for (int i = 0; i < 64; ++i) acc[i] = 0.f;
#pragma unroll
    for (int c = 0; c < 4; ++c) {
        if (c < nch) {
            const float w = wc[c] * Linv;
            const u16* po = PartO + (size_t)(pbase + c) * 16384 + (size_t)q * 128 + d0;
#pragma unroll
            for (int i = 0; i < 64; ++i)
                acc[i] += w * bf2f(po[i]);
        }
    }

    u16* op = O + (size_t)(b * SS + qt * 128 + q) * DD + h * HDIM + d0;
#pragma unroll
    for (int j = 0; j < 8; ++j) {
        short8 vv;
#pragma unroll
        for (int e = 0; e < 8; ++e) vv[e] = (short)f2bf(acc[j * 8 + e]);
        *(short8*)(op + j * 8) = vv;
    }
}

extern "C" void kernel_launch(void* const* d_in, const int* in_sizes, int n_in,
                              void* d_out, int out_size, void* d_ws, size_t ws_size,
                              hipStream_t stream)
{
    const float* queries = (const float*)d_in[0];
    const float* keys    = (const float*)d_in[1];
    const float* values  = (const float*)d_in[2];
    // d_in[3] = attention_mask: causal by construction
    const float* wq = (const float*)d_in[4];
    const float* bq = (const float*)d_in[5];
    const float* wk = (const float*)d_in[6];
    const float* bk = (const float*)d_in[7];
    const float* wv = (const float*)d_in[8];
    const float* bv = (const float*)d_in[9];
    const float* wo = (const float*)d_in[10];
    const float* bo = (const float*)d_in[11];

    const int NMD = MM * DD;
    const int NWW = DD * DD;

    u16* qb  = (u16*)d_ws;                      // converted inputs (bf16), contiguous
    u16* wqb = qb  + (size_t)3 * NMD;           // converted weights (wq pre-scaled)
    u16* wob = wqb + (size_t)3 * NWW;
    u16* qw  = wob + (size_t)NWW;               // q proj [M][D] (KSCALE folded)
                                                // kw = qw + NMD; vtw = qw + 2*NMD ([D][M])
    u16* aw  = qw  + (size_t)3 * NMD;           // attention output [M][D]
    u16*   partO  = qb;                         // aliases dead conv buffers
    float* partML = (float*)wqb;
    (void)in_sizes; (void)n_in; (void)out_size; (void)ws_size;

    dim3 blk(256);
    dim3 gridC(2048);
    dim3 gridQKV(MM / 128, DD / 128, 3);        // 1536 blocks
    dim3 gridO(MM / 128, DD / 128);             // 512 blocks
    dim3 gridA(40, HH, BB);                     // 1280 blocks
    dim3 gridX(12, HH, BB);                     // combine: qt 4..15

    conv_all<<<gridC, blk, 0, stream>>>(queries, keys, values, wq, wk, wv, wo, qb);
    gemm_qkv<<<gridQKV, blk, 0, stream>>>(qb, wqb, bq, bk, bv, qw);
    flash_attn<<<gridA, blk, 0, stream>>>(qw, qw + (size_t)NMD, qw + (size_t)2 * NMD, aw,
                                          partO, partML);
    attn_combine<<<gridX, blk, 0, stream>>>(partO, partML, aw);
    gemm_out<<<gridO, blk, 0, stream>>>(aw, wob, bo, (float*)d_out);
}